// Round 1
// 383.107 us; speedup vs baseline: 1.0582x; 1.0582x over previous
//
#include <hip/hip_runtime.h>
#include <math.h>

// Problem constants: B=1024, T=256, D=128, H=64, 4H=256
constexpr int B_ = 1024;
constexpr int T_ = 256;
constexpr int D_ = 128;
constexpr int H_ = 64;
constexpr int G_ = 256;
constexpr int M_ = B_ * T_;

typedef short     v8s __attribute__((ext_vector_type(8)));   // 8 bf16
typedef float     v4f __attribute__((ext_vector_type(4)));   // MFMA acc
typedef _Float16  h2  __attribute__((ext_vector_type(2)));   // packed f16

__device__ __forceinline__ float sigmoidf_(float x) {
    return 1.0f / (1.0f + __expf(-x));
}
// tanh(x) = 2*sigmoid(2x) - 1 ; overflow-safe at both ends
__device__ __forceinline__ float tanhf_(float x) {
    return fmaf(2.0f, 1.0f / (1.0f + __expf(-2.0f * x)), -1.0f);
}
__device__ __forceinline__ unsigned short f2bf(float f) {   // RNE f32->bf16
    unsigned u = __float_as_uint(f);
    u = (u + 0x7fffu + ((u >> 16) & 1u)) >> 16;
    return (unsigned short)u;
}
__device__ __forceinline__ v8s pack8(float4 a, float4 b) {
    v8s r;
    r[0] = (short)f2bf(a.x); r[1] = (short)f2bf(a.y);
    r[2] = (short)f2bf(a.z); r[3] = (short)f2bf(a.w);
    r[4] = (short)f2bf(b.x); r[5] = (short)f2bf(b.y);
    r[6] = (short)f2bf(b.z); r[7] = (short)f2bf(b.w);
    return r;
}
__device__ __forceinline__ unsigned pkh2(float a, float b) {  // 2xf32 -> packed f16
    h2 v; v[0] = (_Float16)a; v[1] = (_Float16)b;
    return __builtin_bit_cast(unsigned, v);
}
// f16x2 dot with f32 accumulate (v_dot2_f32_f16); safe fallback if missing
__device__ __forceinline__ float fdot2_(unsigned a, unsigned b, float c) {
#if __has_builtin(__builtin_amdgcn_fdot2)
    return __builtin_amdgcn_fdot2(__builtin_bit_cast(h2, a),
                                  __builtin_bit_cast(h2, b), c, false);
#else
    h2 ha = __builtin_bit_cast(h2, a), hb = __builtin_bit_cast(h2, b);
    return c + (float)ha[0] * (float)hb[0] + (float)ha[1] * (float)hb[1];
#endif
}

// ---------------------------------------------------------------------------
// Phase 1: xp[b][t][g] (f16, bias folded) = W_ih @ x^T. 1024 blocks
// (16 t x 64 batch-blocks), 256 thr. A-frags (W_ih) + bias live in wave
// registers (proven-resident v8s pattern); x staged once (read exactly once
// chip-wide); C-tiles bounced through LDS so the global store is f16
// gate-contiguous -- exactly phase 2's coalesced read layout.
// ---------------------------------------------------------------------------
__global__ __launch_bounds__(256, 2)
void xproj_f16_kernel(const float* __restrict__ x,       // [B,T,D]
                      const float* __restrict__ W_ih,    // [256,128]
                      const float* __restrict__ b_ih,    // [256]
                      const float* __restrict__ b_hh,    // [256]
                      unsigned short* __restrict__ xp)   // [B][T][256] f16
{
    const int tch  = blockIdx.x;     // 0..15 : t = tch*16 + tl
    const int bblk = blockIdx.y;     // 0..63 : batches bblk*16..+15
    const int tid  = threadIdx.x;
    const int wv   = tid >> 6;
    const int lane = tid & 63;
    const int q    = lane >> 4;
    const int ml   = lane & 15;

    __shared__ __align__(16) unsigned short xs[16][136];   // x tile bf16, pad+8
    __shared__ __align__(16) unsigned short tbuf[16][272]; // [batch][gate] f16

    // ---- wave-resident A-frags + bias: gate tiles gt = cls*4 + wv ----
    v8s afr[4][4];   // [cls][ks]
    v4f bias[4];
    #pragma unroll
    for (int cls = 0; cls < 4; ++cls) {
        const int gr = (cls * 4 + wv) * 16 + ml;       // A m-index = ml
        #pragma unroll
        for (int ks = 0; ks < 4; ++ks) {
            const float* p = W_ih + (size_t)gr * D_ + ks * 32 + q * 8;
            afr[cls][ks] = pack8(((const float4*)p)[0], ((const float4*)p)[1]);
        }
        #pragma unroll
        for (int r = 0; r < 4; ++r) {
            const int g2 = (cls * 4 + wv) * 16 + q * 4 + r;   // C row = q*4+r
            bias[cls][r] = b_ih[g2] + b_hh[g2];
        }
    }

    for (int tl = 0; tl < 16; ++tl) {
        const int t = tch * 16 + tl;

        // ---- stage x tile: 16 batches x 128 f32 -> bf16 LDS ----
        #pragma unroll
        for (int i = 0; i < 2; ++i) {
            int f4  = tid + i * 256;          // 512 float4s
            int row = f4 >> 5, c4 = f4 & 31;
            float4 v = ((const float4*)(x + ((size_t)(bblk * 16 + row) * T_
                                             + t) * D_))[c4];
            short4 s;
            s.x = (short)f2bf(v.x); s.y = (short)f2bf(v.y);
            s.z = (short)f2bf(v.z); s.w = (short)f2bf(v.w);
            *(short4*)&xs[row][c4 * 4] = s;
        }
        __syncthreads();   // bar1: xs ready (also protects prev tbuf readers)

        // ---- MFMA: 4 C-tiles per wave, K=128 ----
        v4f acc[4];
        #pragma unroll
        for (int cls = 0; cls < 4; ++cls) acc[cls] = bias[cls];
        #pragma unroll
        for (int ks = 0; ks < 4; ++ks) {
            v8s bf = *(const v8s*)&xs[ml][ks * 32 + q * 8];   // B: n=ml, k
            #pragma unroll
            for (int cls = 0; cls < 4; ++cls)
                acc[cls] = __builtin_amdgcn_mfma_f32_16x16x32_bf16(
                    afr[cls][ks], bf, acc[cls], 0, 0, 0);
        }

        // ---- pack f16 -> tbuf[batch=ml][gate] ----
        #pragma unroll
        for (int cls = 0; cls < 4; ++cls) {
            uint2 pk;
            pk.x = pkh2(acc[cls][0], acc[cls][1]);
            pk.y = pkh2(acc[cls][2], acc[cls][3]);
            *(uint2*)&tbuf[ml][cls * 64 + wv * 16 + q * 4] = pk;
        }
        __syncthreads();   // bar2: tbuf ready; all xs reads done

        // ---- coalesced store: thread covers 16 gates of one (b,t) row ----
        {
            const int br = tid >> 4, seg = tid & 15;
            uint4 r0 = *(const uint4*)&tbuf[br][seg * 16];
            uint4 r1 = *(const uint4*)&tbuf[br][seg * 16 + 8];
            unsigned short* orow = xp + ((size_t)(bblk * 16 + br) * T_ + t) * G_
                                      + seg * 16;
            *(uint4*)orow       = r0;
            *(uint4*)(orow + 8) = r1;
        }
    }
}

// ---------------------------------------------------------------------------
// Phase 2 (NEW): fully wave-synchronous recurrence. One 64-lane wave per
// batch element (1024 blocks x 64 thr). Lane l owns gate rows
// {l, 64+l, 128+l, 192+l}, so i/f/g/o for hidden unit l are lane-local and
// the cell update needs NO cross-lane traffic. W_hh lives in 128 VGPRs as
// packed f16 (4 rows x 8 uint4). h is exchanged via a 128B LDS buffer with
// a bare s_waitcnt lgkmcnt(0) -- no s_barrier, no vmcnt drain, so the
// next-step xp prefetch stays in flight across the step boundary.
// Matvec: 128 v_dot2_f32_f16 per lane per step (work-conserved vs old
// kernel), zero barriers vs 512 block barriers before.
// ---------------------------------------------------------------------------
__global__ __launch_bounds__(64, 1)
void rec_wave_kernel(const unsigned short* __restrict__ xp,  // [B][T][256] f16
                     const float* __restrict__ W_hh,   // [256,64]
                     const float* __restrict__ W1,     // [32,64]
                     const float* __restrict__ b1,     // [32]
                     const float* __restrict__ W2,     // [1,32]
                     const float* __restrict__ b2,     // [1]
                     float* __restrict__ out)          // [B]
{
    const int b    = blockIdx.x;
    const int lane = threadIdx.x;    // 0..63

    __shared__ __align__(16) unsigned hb[2][32];   // h as 64 f16, dbuf
    __shared__ float hf[H_];
    __shared__ float ys[32];

    // ---- W_hh rows {lane, 64+lane, 128+lane, 192+lane} -> 32 uint4 ----
    uint4 wp[4][8];
    #pragma unroll
    for (int r = 0; r < 4; ++r) {
        const float* p = W_hh + (size_t)(r * H_ * 4 + lane) * H_ / 4;
        // NOTE: row index is r*64 + lane, row length H_=64:
        p = W_hh + (size_t)(r * 64 + lane) * H_;
        #pragma unroll
        for (int k8 = 0; k8 < 8; ++k8) {
            float4 v0 = ((const float4*)(p + k8 * 8))[0];
            float4 v1 = ((const float4*)(p + k8 * 8))[1];
            wp[r][k8].x = pkh2(v0.x, v0.y);
            wp[r][k8].y = pkh2(v0.z, v0.w);
            wp[r][k8].z = pkh2(v1.x, v1.y);
            wp[r][k8].w = pkh2(v1.z, v1.w);
        }
    }

    if (lane < 32) { hb[0][lane] = 0u; hb[1][lane] = 0u; }  // h(0) = 0
    float c = 0.0f, hval = 0.0f;

    const unsigned short* __restrict__ xptr = xp + (size_t)b * T_ * G_ + lane;
    // preload t=0 gates (coalesced 128B per 64-lane load, x4)
    unsigned short xv0 = xptr[0],   xv1 = xptr[64];
    unsigned short xv2 = xptr[128], xv3 = xptr[192];
    __syncthreads();   // once: hb zeros visible

    for (int t = 0; t < T_; ++t) {
        // ---- prefetch next step's xp (consumed after this step's matvec) ----
        const unsigned short* xnp =
            xptr + (size_t)((t + 1 < T_) ? t + 1 : T_ - 1) * G_;
        unsigned short xn0 = xnp[0],   xn1 = xnp[64];
        unsigned short xn2 = xnp[128], xn3 = xnp[192];

        // ---- matvec: 4 gate rows x K=64, f16 dot2, f32 accumulate ----
        const int par = t & 1;
        const uint4* hb4 = (const uint4*)hb[par];
        float a0[4] = {0.f, 0.f, 0.f, 0.f};
        float a1[4] = {0.f, 0.f, 0.f, 0.f};
        #pragma unroll
        for (int k8 = 0; k8 < 8; ++k8) {
            uint4 hv = hb4[k8];              // broadcast b128, conflict-free
            #pragma unroll
            for (int r = 0; r < 4; ++r) {
                a0[r] = fdot2_(wp[r][k8].x, hv.x, a0[r]);
                a1[r] = fdot2_(wp[r][k8].y, hv.y, a1[r]);
                a0[r] = fdot2_(wp[r][k8].z, hv.z, a0[r]);
                a1[r] = fdot2_(wp[r][k8].w, hv.w, a1[r]);
            }
        }
        float pre0 = (float)__builtin_bit_cast(_Float16, xv0) + (a0[0] + a1[0]);
        float pre1 = (float)__builtin_bit_cast(_Float16, xv1) + (a0[1] + a1[1]);
        float pre2 = (float)__builtin_bit_cast(_Float16, xv2) + (a0[2] + a1[2]);
        float pre3 = (float)__builtin_bit_cast(_Float16, xv3) + (a0[3] + a1[3]);

        // ---- lane-local gate activations + cell update ----
        float gi = sigmoidf_(pre0);
        float gf = sigmoidf_(pre1);
        float gg = tanhf_(pre2);
        float go = sigmoidf_(pre3);
        c    = fmaf(gf, c, gi * gg);
        hval = go * tanhf_(c);

        // ---- publish h(t+1): 2B/lane, then LDS-only fence (no barrier) ----
        ((_Float16*)hb[par ^ 1])[lane] = (_Float16)hval;
        asm volatile("s_waitcnt lgkmcnt(0)" ::: "memory");

        xv0 = xn0; xv1 = xn1; xv2 = xn2; xv3 = xn3;
    }

    // ---- head (once) ----
    hf[lane] = hval;
    __syncthreads();
    if (lane < 32) {
        float acc = b1[lane];
        const float4* w1r = (const float4*)(W1 + (size_t)lane * H_);
        #pragma unroll
        for (int k4 = 0; k4 < 16; ++k4) {
            float4 h4 = *(const float4*)&hf[k4 * 4];
            float4 w4 = w1r[k4];
            acc = fmaf(w4.x, h4.x, acc); acc = fmaf(w4.y, h4.y, acc);
            acc = fmaf(w4.z, h4.z, acc); acc = fmaf(w4.w, h4.w, acc);
        }
        ys[lane] = fmaxf(acc, 0.0f);
    }
    __syncthreads();
    if (lane == 0) {
        float acc = b2[0];
        #pragma unroll
        for (int j = 0; j < 32; ++j) acc = fmaf(W2[j], ys[j], acc);
        out[b] = sigmoidf_(acc);
    }
}

// ---------------------------------------------------------------------------
// Fallback: round-1 fused fp32 kernel (used only if workspace too small).
// ---------------------------------------------------------------------------
__global__ __launch_bounds__(256, 2)
void lstm_fused_kernel(const float* __restrict__ x,
                       const float* __restrict__ W_ih,
                       const float* __restrict__ W_hh,
                       const float* __restrict__ b_ih,
                       const float* __restrict__ b_hh,
                       const float* __restrict__ W1,
                       const float* __restrict__ b1,
                       const float* __restrict__ W2,
                       const float* __restrict__ b2,
                       float* __restrict__ out)
{
    const int b = blockIdx.x;
    const int g = threadIdx.x;

    __shared__ __align__(16) float xs[D_];
    __shared__ __align__(16) float hs[H_];
    __shared__ __align__(16) float gts[G_];
    __shared__ __align__(16) float yss[32];

    float wih[D_];
    float whhr[H_];
    {
        const float4* wr = (const float4*)(W_ih + (size_t)g * D_);
        #pragma unroll
        for (int k = 0; k < D_ / 4; ++k) {
            float4 v = wr[k];
            wih[4*k+0] = v.x; wih[4*k+1] = v.y;
            wih[4*k+2] = v.z; wih[4*k+3] = v.w;
        }
    }
    {
        const float4* wr = (const float4*)(W_hh + (size_t)g * H_);
        #pragma unroll
        for (int k = 0; k < H_ / 4; ++k) {
            float4 v = wr[k];
            whhr[4*k+0] = v.x; whhr[4*k+1] = v.y;
            whhr[4*k+2] = v.z; whhr[4*k+3] = v.w;
        }
    }
    const float bg  = b_ih[g] + b_hh[g];
    const int   cls = g >> 6;

    float c = 0.0f;
    if (g < H_) hs[g] = 0.0f;

    const float* __restrict__ xrow = x + (size_t)b * T_ * D_;

    for (int t = 0; t < T_; ++t) {
        if (g < D_) xs[g] = xrow[(size_t)t * D_ + g];
        __syncthreads();

        float a0 = bg, a1 = 0.f, a2 = 0.f, a3 = 0.f;
        const float4* xs4 = (const float4*)xs;
        #pragma unroll
        for (int k = 0; k < D_ / 4; ++k) {
            float4 v = xs4[k];
            a0 = fmaf(wih[4*k+0], v.x, a0);
            a1 = fmaf(wih[4*k+1], v.y, a1);
            a2 = fmaf(wih[4*k+2], v.z, a2);
            a3 = fmaf(wih[4*k+3], v.w, a3);
        }
        const float4* hs4 = (const float4*)hs;
        #pragma unroll
        for (int k = 0; k < H_ / 4; ++k) {
            float4 v = hs4[k];
            a0 = fmaf(whhr[4*k+0], v.x, a0);
            a1 = fmaf(whhr[4*k+1], v.y, a1);
            a2 = fmaf(whhr[4*k+2], v.z, a2);
            a3 = fmaf(whhr[4*k+3], v.w, a3);
        }
        float acc = (a0 + a1) + (a2 + a3);
        gts[g] = (cls == 2) ? tanhf_(acc) : sigmoidf_(acc);
        __syncthreads();

        if (g < H_) {
            float gi = gts[g];
            float gf = gts[H_ + g];
            float gg = gts[2 * H_ + g];
            float go = gts[3 * H_ + g];
            c = fmaf(gf, c, gi * gg);
            hs[g] = go * tanhf_(c);
        }
    }
    __syncthreads();

    if (g < 32) {
        float acc = b1[g];
        const float* w1r = W1 + g * H_;
        #pragma unroll
        for (int k = 0; k < H_; ++k) acc = fmaf(w1r[k], hs[k], acc);
        yss[g] = fmaxf(acc, 0.0f);
    }
    __syncthreads();
    if (g == 0) {
        float acc = b2[0];
        #pragma unroll
        for (int k = 0; k < 32; ++k) acc = fmaf(W2[k], yss[k], acc);
        out[b] = sigmoidf_(acc);
    }
}

extern "C" void kernel_launch(void* const* d_in, const int* in_sizes, int n_in,
                              void* d_out, int out_size, void* d_ws, size_t ws_size,
                              hipStream_t stream) {
    const float* x    = (const float*)d_in[0];
    const float* W_ih = (const float*)d_in[1];
    const float* W_hh = (const float*)d_in[2];
    const float* b_ih = (const float*)d_in[3];
    const float* b_hh = (const float*)d_in[4];
    const float* W1   = (const float*)d_in[5];
    const float* b1   = (const float*)d_in[6];
    const float* W2   = (const float*)d_in[7];
    const float* b2   = (const float*)d_in[8];
    float* out = (float*)d_out;

    const size_t xp_bytes = (size_t)M_ * G_ * sizeof(unsigned short);  // 134 MB

    if (ws_size >= xp_bytes) {
        unsigned short* xp = (unsigned short*)d_ws;
        xproj_f16_kernel<<<dim3(16, 64), dim3(256), 0, stream>>>(
            x, W_ih, b_ih, b_hh, xp);
        rec_wave_kernel<<<dim3(B_), dim3(64), 0, stream>>>(
            xp, W_hh, W1, b1, W2, b2, out);
    } else {
        lstm_fused_kernel<<<dim3(B_), dim3(256), 0, stream>>>(
            x, W_ih, W_hh, b_ih, b_hh, W1, b1, W2, b2, out);
    }
}